// Round 7
// baseline (709.252 us; speedup 1.0000x reference)
//
#include <hip/hip_runtime.h>
#include <stdint.h>

#define BN_EPS 0.001f

typedef float v2f __attribute__((ext_vector_type(2)));

// ---------------------------------------------------------------------------
// R16 = R15 with the s_sleep constant-arg compile fix (builtin requires a
// literal; runtime ternary split into two constant calls).
// R15 theory (untested due to compile error): R14's ~54us residual above the
// 571us fps floor matches issue-slot/LDS-bandwidth contention from the
// co-resident second block on each fps CU (2 blocks/CU, mapping undefined,
// workers ~26% busy with dense-FMA MLP loops on the same SIMDs). Fix: drop
// the LDS union — FpsSh + WrkSh as SEPARATE static __shared__ (103.4 KB) ->
// hardware can place only 1 block/CU -> fps blocks own their CUs.
// Grid 512: gen-1 = fps(8) + workers(248) exactly fill 256 CUs; 256 tail
// blocks are gen-2, launched as workers retire (184 workers finish before
// fps ends -> tails resident by the final publish). Workers cover j<248
// (centroids <992, ready at the early-992 publish); tails run one
// single-centroid pipeline each for 992..1023 (~11us end-phase).
// All FP math verbatim; publish-covers-data ordering identical to R12-R14
// (every publish follows a vmcnt(0) covering its stores) -> absmax 0.0.
// fps inner loop untouched (R4 frozen).
// ---------------------------------------------------------------------------

struct FpsSh {
  float px[4096], py[4096], pz[4096];
  unsigned long long wk[2][4];   // double-buffered wave winners
  int curh[32];                  // current chunk's centroid history
};

struct WrkSh {
  float W0s[67 * 64];            // 16.75 KB
  float W1s[64 * 64];            // 16 KB
  float sh[64 * 36];             // union: inT (67x34) / h1T (64x36)
  float h0T[64 * 34];            // also pmax in epilogue
  float s0c[64], t0c[64], s1c[64], t1c[64], s2c[128], t2c[128];
  float idxs[4 * 32];            // ballq results for up to 4 centroids
  float cent[4 * 3];             // centroid coords
};

__global__ __launch_bounds__(256) void fused_kernel(
    const float* __restrict__ xyz, const float* __restrict__ points,
    const float* __restrict__ W0, const float* __restrict__ g0,
    const float* __restrict__ b0, const float* __restrict__ m0,
    const float* __restrict__ v0, const float* __restrict__ W1,
    const float* __restrict__ g1, const float* __restrict__ b1,
    const float* __restrict__ m1, const float* __restrict__ v1,
    const float* __restrict__ W2, const float* __restrict__ g2,
    const float* __restrict__ b2, const float* __restrict__ m2,
    const float* __restrict__ v2, float* __restrict__ new_xyz,
    float* __restrict__ new_points, float* __restrict__ idxf,
    unsigned int* __restrict__ prog) {
  // SEPARATE allocations (no union): 49,344 + 54,064 = 103,408 B static LDS.
  // This is deliberate — it forces 1 block/CU, isolating the fps chain.
  __shared__ __align__(16) FpsSh smemF;
  __shared__ __align__(16) WrkSh smemW;
  const int bid = blockIdx.x;
  const int t = threadIdx.x;

  if (bid < 8) {
    // ================= FPS producer (R4 inner loop, untouched) =============
#pragma clang fp contract(off)
    float* px = smemF.px;
    float* py = smemF.py;
    float* pz = smemF.pz;
    int* curh = smemF.curh;
    auto& wk = smemF.wk;
    const int lane = t & 63, wid = t >> 6;
    const int b = bid;
    const float* X = xyz + (size_t)b * 4096 * 3;
    float* out = new_xyz + (size_t)b * 1024 * 3;
    v2f x[8], y[8], z[8], dist[8];
#pragma unroll
    for (int j = 0; j < 8; ++j) {
      const int n0 = (2 * j) * 256 + t;
      const int n1 = (2 * j + 1) * 256 + t;
      x[j].x = X[n0 * 3 + 0]; x[j].y = X[n1 * 3 + 0];
      y[j].x = X[n0 * 3 + 1]; y[j].y = X[n1 * 3 + 1];
      z[j].x = X[n0 * 3 + 2]; z[j].y = X[n1 * 3 + 2];
      px[n0] = x[j].x; py[n0] = y[j].x; pz[n0] = z[j].x;
      px[n1] = x[j].y; py[n1] = y[j].y; pz[n1] = z[j].y;
      dist[j] = (v2f){1e10f, 1e10f};
    }
    __syncthreads();
    int cur = 0;
    for (int cc = 0; cc < 32; ++cc) {
      for (int ii = 0; ii < 32; ++ii) {
        const int it = cc * 32 + ii;
        if (t == 0) curh[ii] = cur;        // LDS only: no vmcnt on the barrier
        const float cx = px[cur], cy = py[cur], cz = pz[cur];
        const v2f cxv = {cx, cx}, cyv = {cy, cy}, czv = {cz, cz};
        float bestv = -1.0f;
        int bestj = 0;
#pragma unroll
        for (int j = 0; j < 8; ++j) {
          v2f dx = x[j] - cxv, dy = y[j] - cyv, dz = z[j] - czv;
          v2f d = dx * dx + dy * dy;   // contract off: mul,mul,add — matches ref
          d = d + dz * dz;
          v2f nd = __builtin_elementwise_min(dist[j], d);
          dist[j] = nd;
          if (nd.x > bestv) { bestv = nd.x; bestj = 2 * j; }      // strict >
          if (nd.y > bestv) { bestv = nd.y; bestj = 2 * j + 1; }
        }
        const int besti = bestj * 256 + t;
        unsigned long long key =
            ((unsigned long long)__float_as_uint(bestv) << 32) | (unsigned)(~besti);
        // ---- wave64 max-reduce via DPP; result lands in lane 63 ----
#define DPP_STEP(CTRL)                                                                     \
        {                                                                                  \
          unsigned lo_ = (unsigned)key, hi_ = (unsigned)(key >> 32);                       \
          unsigned ls = (unsigned)__builtin_amdgcn_update_dpp((int)lo_, (int)lo_, CTRL, 0xf, 0xf, false); \
          unsigned hs = (unsigned)__builtin_amdgcn_update_dpp((int)hi_, (int)hi_, CTRL, 0xf, 0xf, false); \
          unsigned long long sk = ((unsigned long long)hs << 32) | ls;                     \
          if (sk > key) key = sk;                                                          \
        }
        DPP_STEP(0x111)  // row_shr:1
        DPP_STEP(0x112)  // row_shr:2
        DPP_STEP(0x114)  // row_shr:4
        DPP_STEP(0x118)  // row_shr:8
        DPP_STEP(0x142)  // row_bcast:15
        DPP_STEP(0x143)  // row_bcast:31
#undef DPP_STEP
        const unsigned whi = (unsigned)__builtin_amdgcn_readlane((int)(key >> 32), 63);
        const unsigned wlo = (unsigned)__builtin_amdgcn_readlane((int)key, 63);
        if (lane == 0) wk[it & 1][wid] = ((unsigned long long)whi << 32) | wlo;
        __syncthreads();
        const unsigned long long k0 = wk[it & 1][0], k1 = wk[it & 1][1];
        const unsigned long long k2 = wk[it & 1][2], k3 = wk[it & 1][3];
        unsigned long long b01 = (k1 > k0) ? k1 : k0;
        unsigned long long b23 = (k3 > k2) ? k3 : k2;
        unsigned long long bk = (b23 > b01) ? b23 : b01;
        cur = (int)(~(unsigned)(bk & 0xffffffffull));
      }
      // ---- chunk flush: deferred publish (prev chunk), then this chunk's
      // stores. No barrier: flush reads (curh/px) are ordered by the last
      // inner barrier; only wave0 touches them; other waves proceed.
      if (t == 0) {
        // cc-1's stores were issued ~17.8us ago -> this waitcnt is free, and
        // it architecturally orders data ahead of the publish flag.
        asm volatile("s_waitcnt vmcnt(0)" ::: "memory");
        if (cc > 0)
          __hip_atomic_store(&prog[b * 32], (unsigned)(cc * 32),
                             __ATOMIC_RELAXED, __HIP_MEMORY_SCOPE_AGENT);
      }
      if (t < 32) {
        const int c = curh[t];
        const int p = cc * 32 + t;
        __hip_atomic_store(&out[p * 3 + 0], px[c], __ATOMIC_RELAXED,
                           __HIP_MEMORY_SCOPE_AGENT);
        __hip_atomic_store(&out[p * 3 + 1], py[c], __ATOMIC_RELAXED,
                           __HIP_MEMORY_SCOPE_AGENT);
        __hip_atomic_store(&out[p * 3 + 2], pz[c], __ATOMIC_RELAXED,
                           __HIP_MEMORY_SCOPE_AGENT);
      }
      // ---- EARLY 992 PUBLISH: chunk 30's stores just issued; drain them
      // (~0.4us, wave0 only, once) and publish so centroids 960..991 and all
      // remaining worker groups run DURING chunk 31 instead of after fps.
      if (cc == 30 && t == 0) {
        asm volatile("s_waitcnt vmcnt(0)" ::: "memory");
        __hip_atomic_store(&prog[b * 32], 992u, __ATOMIC_RELAXED,
                           __HIP_MEMORY_SCOPE_AGENT);
      }
    }
    // ---- final publish: one-time ~0.3us drain off the loop ----
    if (t == 0) {
      asm volatile("s_waitcnt vmcnt(0)" ::: "memory");
      __hip_atomic_store(&prog[b * 32], 1024u, __ATOMIC_RELAXED,
                         __HIP_MEMORY_SCOPE_AGENT);
    }
    return;
  }

  // ================= worker: ballq + MLP =================================
  float* W0s = smemW.W0s;
  float* W1s = smemW.W1s;
  float* s0c = smemW.s0c; float* t0c = smemW.t0c;
  float* s1c = smemW.s1c; float* t1c = smemW.t1c;
  float* s2c = smemW.s2c; float* t2c = smemW.t2c;
  for (int i = t; i < 67 * 64; i += 256) W0s[i] = W0[i];
  for (int i = t; i < 64 * 64; i += 256) W1s[i] = W1[i];
  if (t < 64) {
    float s = g0[t] * rsqrtf(v0[t] + BN_EPS); s0c[t] = s; t0c[t] = b0[t] - m0[t] * s;
    float u = g1[t] * rsqrtf(v1[t] + BN_EPS); s1c[t] = u; t1c[t] = b1[t] - m1[t] * u;
  }
  if (t < 128) {
    float s = g2[t] * rsqrtf(v2[t] + BN_EPS); s2c[t] = s; t2c[t] = b2[t] - m2[t] * s;
  }
  __syncthreads();
  const int sgrp = t & 15, dgrp = t >> 4;  // L0/L1 tiling
  const int dg2 = t & 31, sg2 = t >> 5;    // L2 tiling
  float* inT = smemW.sh;                   // [c][s] stride 34, gather..L0
  float* h1T = smemW.sh;                   // [d][s] stride 36, L1..L2
  float* h0T = smemW.h0T;
  float* pmax = h0T;                       // alias (h0T dead by L2 epilogue)

  // Adaptive spin-wait: coarse sleep (~1.7us) while >1 chunk away, fine
  // (~0.2us) when close. Relaxed agent loads (sc1): fresh, no cache maint.
  // s_sleep builtin needs a LITERAL arg -> branch to two constant calls.
  auto wait_prog = [&](int b, unsigned need) {
    int guard = 0;
    for (;;) {
      const unsigned p = __hip_atomic_load(&prog[b * 32], __ATOMIC_RELAXED,
                                           __HIP_MEMORY_SCOPE_AGENT);
      if (p >= need) break;
      if (need - p > 32) {
        __builtin_amdgcn_s_sleep(64);
      } else {
        __builtin_amdgcn_s_sleep(8);
      }
      if (++guard > (1 << 20)) break;   // failsafe: never hang the harness
    }
  };

  // ballq + MLP for nc centroids starting at (batch b, point p0).
  auto process_group = [&](int b, int p0, int nc) {
    // ---- ball query: wave wv handles centroid p0+wv. Software-pipelined:
    // prefetch chunk c+1's xyz while ballot-compacting chunk c (FPS picks
    // isolated points -> early-exit rarely fires early; the load latency was
    // on the serial chain). FP math per point verbatim. ----
    {
#pragma clang fp contract(off)
      const int wv = t >> 6, lane = t & 63;
      if (wv < nc) {
        const int pg = b * 1024 + p0 + wv;
        const float* X = xyz + (size_t)b * 4096 * 3;
        const float cx = __hip_atomic_load(&new_xyz[pg * 3 + 0], __ATOMIC_RELAXED,
                                           __HIP_MEMORY_SCOPE_AGENT);
        const float cy = __hip_atomic_load(&new_xyz[pg * 3 + 1], __ATOMIC_RELAXED,
                                           __HIP_MEMORY_SCOPE_AGENT);
        const float cz = __hip_atomic_load(&new_xyz[pg * 3 + 2], __ATOMIC_RELAXED,
                                           __HIP_MEMORY_SCOPE_AGENT);
        const float csq = (cx * cx + cy * cy) + cz * cz;
        float* outg = idxf + (size_t)pg * 32;
        float* ol = smemW.idxs + wv * 32;
        int total = 0;
        int first = -1;
        float xx = X[lane * 3 + 0], yy = X[lane * 3 + 1], zz = X[lane * 3 + 2];
        for (int chunk = 0; chunk < 64; ++chunk) {
          const int n = chunk * 64 + lane;
          float nx = xx, ny = yy, nz = zz;
          if (chunk < 63) {
            const float* Xn = X + (n + 64) * 3;
            nx = Xn[0]; ny = Xn[1]; nz = Xn[2];
          }
          const float sq = (xx * xx + yy * yy) + zz * zz;
          const float dot = fmaf(cz, zz, fmaf(cy, yy, cx * xx));  // gemm K-chain
          const float d2 = (csq + sq) - 2.0f * dot;
          const bool in = d2 < 0.04f;
          const unsigned long long mask = __ballot(in);
          if (first < 0 && mask != 0ull) first = chunk * 64 + __builtin_ctzll(mask);
          if (in) {
            const int pos = total + __builtin_popcountll(mask & ((1ull << lane) - 1ull));
            if (pos < 32) { outg[pos] = (float)n; ol[pos] = (float)n; }
          }
          total += __builtin_popcountll(mask);
          if (total >= 32) break;
          xx = nx; yy = ny; zz = nz;
        }
        if (total < 32 && first >= 0) {
          const int slot = total + lane;
          if (slot < 32) { outg[slot] = (float)first; ol[slot] = (float)first; }
        }
        if (lane == 0) {
          smemW.cent[wv * 3 + 0] = cx;
          smemW.cent[wv * 3 + 1] = cy;
          smemW.cent[wv * 3 + 2] = cz;
        }
      }
    }
    __syncthreads();
    // ---- MLP: nc centroids sequentially (verbatim R9 math) ----
    for (int pp = 0; pp < nc; ++pp) {
      const int pg = b * 1024 + p0 + pp;
      const float cx = smemW.cent[pp * 3 + 0];
      const float cy = smemW.cent[pp * 3 + 1];
      const float cz = smemW.cent[pp * 3 + 2];
      // ---- gather stage (writes inT) ----
      {
        const int s = t >> 3, cg = t & 7;
        const int i = (int)smemW.idxs[pp * 32 + s];
        const float* Pr = points + ((size_t)b * 4096 + i) * 64 + cg * 8;
        const float4 a = *(const float4*)Pr;
        const float4 c4 = *(const float4*)(Pr + 4);
        const int r = 3 + cg * 8;
        inT[(r + 0) * 34 + s] = a.x;  inT[(r + 1) * 34 + s] = a.y;
        inT[(r + 2) * 34 + s] = a.z;  inT[(r + 3) * 34 + s] = a.w;
        inT[(r + 4) * 34 + s] = c4.x; inT[(r + 5) * 34 + s] = c4.y;
        inT[(r + 6) * 34 + s] = c4.z; inT[(r + 7) * 34 + s] = c4.w;
        if (t < 32) {
          const int i2 = (int)smemW.idxs[pp * 32 + t];
          const float* Xr = xyz + ((size_t)b * 4096 + i2) * 3;
          inT[0 * 34 + t] = Xr[0] - cx;
          inT[1 * 34 + t] = Xr[1] - cy;
          inT[2 * 34 + t] = Xr[2] - cz;
        }
      }
      __syncthreads();
      // ---- L0: 67 -> 64 ----
      {
        float acc[2][4] = {{0, 0, 0, 0}, {0, 0, 0, 0}};
#pragma unroll 4
        for (int c = 0; c < 67; ++c) {
          const float2 a = *(const float2*)&inT[c * 34 + 2 * sgrp];
          const float4 w = *(const float4*)&W0s[c * 64 + 4 * dgrp];
          acc[0][0] = fmaf(a.x, w.x, acc[0][0]); acc[0][1] = fmaf(a.x, w.y, acc[0][1]);
          acc[0][2] = fmaf(a.x, w.z, acc[0][2]); acc[0][3] = fmaf(a.x, w.w, acc[0][3]);
          acc[1][0] = fmaf(a.y, w.x, acc[1][0]); acc[1][1] = fmaf(a.y, w.y, acc[1][1]);
          acc[1][2] = fmaf(a.y, w.z, acc[1][2]); acc[1][3] = fmaf(a.y, w.w, acc[1][3]);
        }
#pragma unroll
        for (int dj = 0; dj < 4; ++dj) {
          const int d = 4 * dgrp + dj;
          const float s = s0c[d], bb = t0c[d];
#pragma unroll
          for (int si = 0; si < 2; ++si) {
            float yv = fmaf(acc[si][dj], s, bb);
            h0T[d * 34 + 2 * sgrp + si] = fmaxf(yv, 0.0f);
          }
        }
      }
      __syncthreads();
      // ---- L1: 64 -> 64 ----
      {
        float acc[2][4] = {{0, 0, 0, 0}, {0, 0, 0, 0}};
#pragma unroll 4
        for (int c = 0; c < 64; ++c) {
          const float2 a = *(const float2*)&h0T[c * 34 + 2 * sgrp];
          const float4 w = *(const float4*)&W1s[c * 64 + 4 * dgrp];
          acc[0][0] = fmaf(a.x, w.x, acc[0][0]); acc[0][1] = fmaf(a.x, w.y, acc[0][1]);
          acc[0][2] = fmaf(a.x, w.z, acc[0][2]); acc[0][3] = fmaf(a.x, w.w, acc[0][3]);
          acc[1][0] = fmaf(a.y, w.x, acc[1][0]); acc[1][1] = fmaf(a.y, w.y, acc[1][1]);
          acc[1][2] = fmaf(a.y, w.z, acc[1][2]); acc[1][3] = fmaf(a.y, w.w, acc[1][3]);
        }
#pragma unroll
        for (int dj = 0; dj < 4; ++dj) {
          const int d = 4 * dgrp + dj;
          const float s = s1c[d], bb = t1c[d];
#pragma unroll
          for (int si = 0; si < 2; ++si) {
            float yv = fmaf(acc[si][dj], s, bb);
            h1T[d * 36 + 2 * sgrp + si] = fmaxf(yv, 0.0f);
          }
        }
      }
      __syncthreads();
      // ---- L2: 64 -> 128, fused BN+ReLU+max ----
      {
        float acc[4][4] = {{0,0,0,0},{0,0,0,0},{0,0,0,0},{0,0,0,0}};
#pragma unroll 8
        for (int c = 0; c < 64; ++c) {
          const float4 a = *(const float4*)&h1T[c * 36 + 4 * sg2];
          const float4 w = *(const float4*)(W2 + c * 128 + 4 * dg2);
          acc[0][0] = fmaf(a.x, w.x, acc[0][0]); acc[0][1] = fmaf(a.x, w.y, acc[0][1]);
          acc[0][2] = fmaf(a.x, w.z, acc[0][2]); acc[0][3] = fmaf(a.x, w.w, acc[0][3]);
          acc[1][0] = fmaf(a.y, w.x, acc[1][0]); acc[1][1] = fmaf(a.y, w.y, acc[1][1]);
          acc[1][2] = fmaf(a.y, w.z, acc[1][2]); acc[1][3] = fmaf(a.y, w.w, acc[1][3]);
          acc[2][0] = fmaf(a.z, w.x, acc[2][0]); acc[2][1] = fmaf(a.z, w.y, acc[2][1]);
          acc[2][2] = fmaf(a.z, w.z, acc[2][2]); acc[2][3] = fmaf(a.z, w.w, acc[2][3]);
          acc[3][0] = fmaf(a.w, w.x, acc[3][0]); acc[3][1] = fmaf(a.w, w.y, acc[3][1]);
          acc[3][2] = fmaf(a.w, w.z, acc[3][2]); acc[3][3] = fmaf(a.w, w.w, acc[3][3]);
        }
#pragma unroll
        for (int dj = 0; dj < 4; ++dj) {
          const int d = 4 * dg2 + dj;
          const float s = s2c[d], bb = t2c[d];
          float mx = 0.0f;  // relu outputs are >= 0
#pragma unroll
          for (int si = 0; si < 4; ++si) {
            float yv = fmaf(acc[si][dj], s, bb);
            mx = fmaxf(mx, fmaxf(yv, 0.0f));
          }
          pmax[sg2 * 128 + d] = mx;
        }
      }
      __syncthreads();
      if (t < 128) {
        float mx = pmax[t];
#pragma unroll
        for (int g = 1; g < 8; ++g) mx = fmaxf(mx, pmax[g * 128 + t]);
        new_points[(size_t)pg * 128 + t] = mx;
      }
      __syncthreads();
    }
  };

  if (bid >= 256) {
    // 256 gen-2 tail blocks (launch as gen-1 workers retire): one
    // single-centroid pipeline each for 992..1023, ready at the final
    // publish. 184 workers finish before fps ends, so most tails are
    // resident and polling by then. End-phase ~= 11us.
    const int sid = bid - 256;          // 0..255
    const int b = sid & 7;              // spread across batches
    const int q = sid >> 3;             // 0..31
    wait_prog(b, (unsigned)(992 + q + 1));
    process_group(b, 992 + q, 1);
  } else {
    // 248 gen-1 workers (1 per CU): j=0..247 (centroids 0..991), 8 groups
    // each, ready-order k = j*8+b. Last groups (j>=240) unlock at the
    // early-992 publish and overlap fps chunk 31.
    for (int k = bid - 8; k < 1984; k += 248) {
      const int j = k >> 3, b = k & 7;
      wait_prog(b, (unsigned)(j * 4 + 4));
      process_group(b, j * 4, 4);
    }
  }
}

extern "C" void kernel_launch(void* const* d_in, const int* in_sizes, int n_in,
                              void* d_out, int out_size, void* d_ws, size_t ws_size,
                              hipStream_t stream) {
  (void)in_sizes; (void)n_in; (void)out_size; (void)ws_size;
  const float* xyz    = (const float*)d_in[0];
  const float* points = (const float*)d_in[1];
  const float* W0 = (const float*)d_in[2];
  const float* g0 = (const float*)d_in[3];
  const float* b0 = (const float*)d_in[4];
  const float* m0 = (const float*)d_in[5];
  const float* v0 = (const float*)d_in[6];
  const float* W1 = (const float*)d_in[7];
  const float* g1 = (const float*)d_in[8];
  const float* b1 = (const float*)d_in[9];
  const float* m1 = (const float*)d_in[10];
  const float* v1 = (const float*)d_in[11];
  const float* W2 = (const float*)d_in[12];
  const float* g2 = (const float*)d_in[13];
  const float* b2 = (const float*)d_in[14];
  const float* m2 = (const float*)d_in[15];
  const float* v2 = (const float*)d_in[16];

  float* new_xyz    = (float*)d_out;                 // 8*1024*3
  float* new_points = new_xyz + 8 * 1024 * 3;        // 8*1024*128
  float* idxf       = new_points + 8 * 1024 * 128;   // 8*1024*32

  unsigned int* prog = (unsigned int*)d_ws;          // 8 counters, 128B apart
  (void)hipMemsetAsync(d_ws, 0, 8 * 32 * sizeof(unsigned int), stream);
  fused_kernel<<<512, 256, 0, stream>>>(xyz, points, W0, g0, b0, m0, v0,
                                        W1, g1, b1, m1, v1,
                                        W2, g2, b2, m2, v2,
                                        new_xyz, new_points, idxf, prog);
}

// Round 8
// 701.703 us; speedup vs baseline: 1.0108x; 1.0108x over previous
//
#include <hip/hip_runtime.h>
#include <stdint.h>

#define BN_EPS 0.001f

typedef float v2f __attribute__((ext_vector_type(2)));

// ---------------------------------------------------------------------------
// R17 = byte-exact revert to R14 (proven 636us steady — best measured).
// R16 DISPROVED the CU-contention theory: forcing 1 block/CU (103KB LDS) did
// NOT speed fps (644 vs 636; +8us from gen-2 tails). The ~54us residual above
// the 571us fps floor is chip-wide clock throttle under load: 571 x 2.4/2.2
// + 11us end-phase = 634us ~= measured 636. Not kernel-addressable — the
// overlap (821 -> 636) strictly dominates the serial alternative.
// Structure: fps (blocks 0..7, R4-frozen inner loop) with deferred per-chunk
// publish + early-992 publish; 248 workers (4-centroid groups, j<240); 256
// tail blocks x two single-centroid pipelines (960+q early, 992+q final).
// Relaxed agent-scope atomics only (no wbl2/inv); every publish follows a
// vmcnt(0) covering its stores. All FP math verbatim -> absmax 0.0.
// ---------------------------------------------------------------------------

struct FpsSh {
  float px[4096], py[4096], pz[4096];
  unsigned long long wk[2][4];   // double-buffered wave winners
  int curh[32];                  // current chunk's centroid history
};

struct WrkSh {
  float W0s[67 * 64];            // 16.75 KB
  float W1s[64 * 64];            // 16 KB
  float sh[64 * 36];             // union: inT (67x34) / h1T (64x36)
  float h0T[64 * 34];            // also pmax in epilogue
  float s0c[64], t0c[64], s1c[64], t1c[64], s2c[128], t2c[128];
  float idxs[4 * 32];            // ballq results for up to 4 centroids
  float cent[4 * 3];             // centroid coords
};

union AllSh {  // 54,064 B -> 2 blocks/CU; grid 512 fully co-resident (proven)
  FpsSh f;
  WrkSh w;
};

__global__ __launch_bounds__(256) void fused_kernel(
    const float* __restrict__ xyz, const float* __restrict__ points,
    const float* __restrict__ W0, const float* __restrict__ g0,
    const float* __restrict__ b0, const float* __restrict__ m0,
    const float* __restrict__ v0, const float* __restrict__ W1,
    const float* __restrict__ g1, const float* __restrict__ b1,
    const float* __restrict__ m1, const float* __restrict__ v1,
    const float* __restrict__ W2, const float* __restrict__ g2,
    const float* __restrict__ b2, const float* __restrict__ m2,
    const float* __restrict__ v2, float* __restrict__ new_xyz,
    float* __restrict__ new_points, float* __restrict__ idxf,
    unsigned int* __restrict__ prog) {
  __shared__ __align__(16) AllSh smem;
  const int bid = blockIdx.x;
  const int t = threadIdx.x;

  if (bid < 8) {
    // ================= FPS producer (R4 inner loop, untouched) =============
#pragma clang fp contract(off)
    float* px = smem.f.px;
    float* py = smem.f.py;
    float* pz = smem.f.pz;
    int* curh = smem.f.curh;
    auto& wk = smem.f.wk;
    const int lane = t & 63, wid = t >> 6;
    const int b = bid;
    const float* X = xyz + (size_t)b * 4096 * 3;
    float* out = new_xyz + (size_t)b * 1024 * 3;
    v2f x[8], y[8], z[8], dist[8];
#pragma unroll
    for (int j = 0; j < 8; ++j) {
      const int n0 = (2 * j) * 256 + t;
      const int n1 = (2 * j + 1) * 256 + t;
      x[j].x = X[n0 * 3 + 0]; x[j].y = X[n1 * 3 + 0];
      y[j].x = X[n0 * 3 + 1]; y[j].y = X[n1 * 3 + 1];
      z[j].x = X[n0 * 3 + 2]; z[j].y = X[n1 * 3 + 2];
      px[n0] = x[j].x; py[n0] = y[j].x; pz[n0] = z[j].x;
      px[n1] = x[j].y; py[n1] = y[j].y; pz[n1] = z[j].y;
      dist[j] = (v2f){1e10f, 1e10f};
    }
    __syncthreads();
    int cur = 0;
    for (int cc = 0; cc < 32; ++cc) {
      for (int ii = 0; ii < 32; ++ii) {
        const int it = cc * 32 + ii;
        if (t == 0) curh[ii] = cur;        // LDS only: no vmcnt on the barrier
        const float cx = px[cur], cy = py[cur], cz = pz[cur];
        const v2f cxv = {cx, cx}, cyv = {cy, cy}, czv = {cz, cz};
        float bestv = -1.0f;
        int bestj = 0;
#pragma unroll
        for (int j = 0; j < 8; ++j) {
          v2f dx = x[j] - cxv, dy = y[j] - cyv, dz = z[j] - czv;
          v2f d = dx * dx + dy * dy;   // contract off: mul,mul,add — matches ref
          d = d + dz * dz;
          v2f nd = __builtin_elementwise_min(dist[j], d);
          dist[j] = nd;
          if (nd.x > bestv) { bestv = nd.x; bestj = 2 * j; }      // strict >
          if (nd.y > bestv) { bestv = nd.y; bestj = 2 * j + 1; }
        }
        const int besti = bestj * 256 + t;
        unsigned long long key =
            ((unsigned long long)__float_as_uint(bestv) << 32) | (unsigned)(~besti);
        // ---- wave64 max-reduce via DPP; result lands in lane 63 ----
#define DPP_STEP(CTRL)                                                                     \
        {                                                                                  \
          unsigned lo_ = (unsigned)key, hi_ = (unsigned)(key >> 32);                       \
          unsigned ls = (unsigned)__builtin_amdgcn_update_dpp((int)lo_, (int)lo_, CTRL, 0xf, 0xf, false); \
          unsigned hs = (unsigned)__builtin_amdgcn_update_dpp((int)hi_, (int)hi_, CTRL, 0xf, 0xf, false); \
          unsigned long long sk = ((unsigned long long)hs << 32) | ls;                     \
          if (sk > key) key = sk;                                                          \
        }
        DPP_STEP(0x111)  // row_shr:1
        DPP_STEP(0x112)  // row_shr:2
        DPP_STEP(0x114)  // row_shr:4
        DPP_STEP(0x118)  // row_shr:8
        DPP_STEP(0x142)  // row_bcast:15
        DPP_STEP(0x143)  // row_bcast:31
#undef DPP_STEP
        const unsigned whi = (unsigned)__builtin_amdgcn_readlane((int)(key >> 32), 63);
        const unsigned wlo = (unsigned)__builtin_amdgcn_readlane((int)key, 63);
        if (lane == 0) wk[it & 1][wid] = ((unsigned long long)whi << 32) | wlo;
        __syncthreads();
        const unsigned long long k0 = wk[it & 1][0], k1 = wk[it & 1][1];
        const unsigned long long k2 = wk[it & 1][2], k3 = wk[it & 1][3];
        unsigned long long b01 = (k1 > k0) ? k1 : k0;
        unsigned long long b23 = (k3 > k2) ? k3 : k2;
        unsigned long long bk = (b23 > b01) ? b23 : b01;
        cur = (int)(~(unsigned)(bk & 0xffffffffull));
      }
      // ---- chunk flush: deferred publish (prev chunk), then this chunk's
      // stores. No barrier: flush reads (curh/px) are ordered by the last
      // inner barrier; only wave0 touches them; other waves proceed.
      if (t == 0) {
        // cc-1's stores were issued ~17.8us ago -> this waitcnt is free, and
        // it architecturally orders data ahead of the publish flag.
        asm volatile("s_waitcnt vmcnt(0)" ::: "memory");
        if (cc > 0)
          __hip_atomic_store(&prog[b * 32], (unsigned)(cc * 32),
                             __ATOMIC_RELAXED, __HIP_MEMORY_SCOPE_AGENT);
      }
      if (t < 32) {
        const int c = curh[t];
        const int p = cc * 32 + t;
        __hip_atomic_store(&out[p * 3 + 0], px[c], __ATOMIC_RELAXED,
                           __HIP_MEMORY_SCOPE_AGENT);
        __hip_atomic_store(&out[p * 3 + 1], py[c], __ATOMIC_RELAXED,
                           __HIP_MEMORY_SCOPE_AGENT);
        __hip_atomic_store(&out[p * 3 + 2], pz[c], __ATOMIC_RELAXED,
                           __HIP_MEMORY_SCOPE_AGENT);
      }
      // ---- EARLY 992 PUBLISH: chunk 30's stores just issued; drain them
      // (~0.4us, wave0 only, once) and publish so centroids 960..991 and all
      // remaining worker groups run DURING chunk 31 instead of after fps.
      if (cc == 30 && t == 0) {
        asm volatile("s_waitcnt vmcnt(0)" ::: "memory");
        __hip_atomic_store(&prog[b * 32], 992u, __ATOMIC_RELAXED,
                           __HIP_MEMORY_SCOPE_AGENT);
      }
    }
    // ---- final publish: one-time ~0.3us drain off the loop ----
    if (t == 0) {
      asm volatile("s_waitcnt vmcnt(0)" ::: "memory");
      __hip_atomic_store(&prog[b * 32], 1024u, __ATOMIC_RELAXED,
                         __HIP_MEMORY_SCOPE_AGENT);
    }
    return;
  }

  // ================= worker: ballq + MLP =================================
  float* W0s = smem.w.W0s;
  float* W1s = smem.w.W1s;
  float* s0c = smem.w.s0c; float* t0c = smem.w.t0c;
  float* s1c = smem.w.s1c; float* t1c = smem.w.t1c;
  float* s2c = smem.w.s2c; float* t2c = smem.w.t2c;
  for (int i = t; i < 67 * 64; i += 256) W0s[i] = W0[i];
  for (int i = t; i < 64 * 64; i += 256) W1s[i] = W1[i];
  if (t < 64) {
    float s = g0[t] * rsqrtf(v0[t] + BN_EPS); s0c[t] = s; t0c[t] = b0[t] - m0[t] * s;
    float u = g1[t] * rsqrtf(v1[t] + BN_EPS); s1c[t] = u; t1c[t] = b1[t] - m1[t] * u;
  }
  if (t < 128) {
    float s = g2[t] * rsqrtf(v2[t] + BN_EPS); s2c[t] = s; t2c[t] = b2[t] - m2[t] * s;
  }
  __syncthreads();
  const int sgrp = t & 15, dgrp = t >> 4;  // L0/L1 tiling
  const int dg2 = t & 31, sg2 = t >> 5;    // L2 tiling
  float* inT = smem.w.sh;                  // [c][s] stride 34, gather..L0
  float* h1T = smem.w.sh;                  // [d][s] stride 36, L1..L2
  float* h0T = smem.w.h0T;
  float* pmax = h0T;                       // alias (h0T dead by L2 epilogue)

  // Spin-wait on per-batch progress (relaxed agent loads: sc1, fresh, no
  // cache maintenance). s_sleep(8) ~= 0.2us wake granularity.
  auto wait_prog = [&](int b, unsigned need) {
    int guard = 0;
    while (__hip_atomic_load(&prog[b * 32], __ATOMIC_RELAXED,
                             __HIP_MEMORY_SCOPE_AGENT) < need) {
      __builtin_amdgcn_s_sleep(8);
      if (++guard > (1 << 20)) break;   // failsafe: never hang the harness
    }
  };

  // ballq + MLP for nc centroids starting at (batch b, point p0).
  auto process_group = [&](int b, int p0, int nc) {
    // ---- ball query: wave wv handles centroid p0+wv. Software-pipelined:
    // prefetch chunk c+1's xyz while ballot-compacting chunk c (FPS picks
    // isolated points -> early-exit rarely fires early; the load latency was
    // on the serial chain). FP math per point verbatim. ----
    {
#pragma clang fp contract(off)
      const int wv = t >> 6, lane = t & 63;
      if (wv < nc) {
        const int pg = b * 1024 + p0 + wv;
        const float* X = xyz + (size_t)b * 4096 * 3;
        const float cx = __hip_atomic_load(&new_xyz[pg * 3 + 0], __ATOMIC_RELAXED,
                                           __HIP_MEMORY_SCOPE_AGENT);
        const float cy = __hip_atomic_load(&new_xyz[pg * 3 + 1], __ATOMIC_RELAXED,
                                           __HIP_MEMORY_SCOPE_AGENT);
        const float cz = __hip_atomic_load(&new_xyz[pg * 3 + 2], __ATOMIC_RELAXED,
                                           __HIP_MEMORY_SCOPE_AGENT);
        const float csq = (cx * cx + cy * cy) + cz * cz;
        float* outg = idxf + (size_t)pg * 32;
        float* ol = smem.w.idxs + wv * 32;
        int total = 0;
        int first = -1;
        float xx = X[lane * 3 + 0], yy = X[lane * 3 + 1], zz = X[lane * 3 + 2];
        for (int chunk = 0; chunk < 64; ++chunk) {
          const int n = chunk * 64 + lane;
          float nx = xx, ny = yy, nz = zz;
          if (chunk < 63) {
            const float* Xn = X + (n + 64) * 3;
            nx = Xn[0]; ny = Xn[1]; nz = Xn[2];
          }
          const float sq = (xx * xx + yy * yy) + zz * zz;
          const float dot = fmaf(cz, zz, fmaf(cy, yy, cx * xx));  // gemm K-chain
          const float d2 = (csq + sq) - 2.0f * dot;
          const bool in = d2 < 0.04f;
          const unsigned long long mask = __ballot(in);
          if (first < 0 && mask != 0ull) first = chunk * 64 + __builtin_ctzll(mask);
          if (in) {
            const int pos = total + __builtin_popcountll(mask & ((1ull << lane) - 1ull));
            if (pos < 32) { outg[pos] = (float)n; ol[pos] = (float)n; }
          }
          total += __builtin_popcountll(mask);
          if (total >= 32) break;
          xx = nx; yy = ny; zz = nz;
        }
        if (total < 32 && first >= 0) {
          const int slot = total + lane;
          if (slot < 32) { outg[slot] = (float)first; ol[slot] = (float)first; }
        }
        if (lane == 0) {
          smem.w.cent[wv * 3 + 0] = cx;
          smem.w.cent[wv * 3 + 1] = cy;
          smem.w.cent[wv * 3 + 2] = cz;
        }
      }
    }
    __syncthreads();
    // ---- MLP: nc centroids sequentially (verbatim R9 math) ----
    for (int pp = 0; pp < nc; ++pp) {
      const int pg = b * 1024 + p0 + pp;
      const float cx = smem.w.cent[pp * 3 + 0];
      const float cy = smem.w.cent[pp * 3 + 1];
      const float cz = smem.w.cent[pp * 3 + 2];
      // ---- gather stage (writes inT) ----
      {
        const int s = t >> 3, cg = t & 7;
        const int i = (int)smem.w.idxs[pp * 32 + s];
        const float* Pr = points + ((size_t)b * 4096 + i) * 64 + cg * 8;
        const float4 a = *(const float4*)Pr;
        const float4 c4 = *(const float4*)(Pr + 4);
        const int r = 3 + cg * 8;
        inT[(r + 0) * 34 + s] = a.x;  inT[(r + 1) * 34 + s] = a.y;
        inT[(r + 2) * 34 + s] = a.z;  inT[(r + 3) * 34 + s] = a.w;
        inT[(r + 4) * 34 + s] = c4.x; inT[(r + 5) * 34 + s] = c4.y;
        inT[(r + 6) * 34 + s] = c4.z; inT[(r + 7) * 34 + s] = c4.w;
        if (t < 32) {
          const int i2 = (int)smem.w.idxs[pp * 32 + t];
          const float* Xr = xyz + ((size_t)b * 4096 + i2) * 3;
          inT[0 * 34 + t] = Xr[0] - cx;
          inT[1 * 34 + t] = Xr[1] - cy;
          inT[2 * 34 + t] = Xr[2] - cz;
        }
      }
      __syncthreads();
      // ---- L0: 67 -> 64 ----
      {
        float acc[2][4] = {{0, 0, 0, 0}, {0, 0, 0, 0}};
#pragma unroll 4
        for (int c = 0; c < 67; ++c) {
          const float2 a = *(const float2*)&inT[c * 34 + 2 * sgrp];
          const float4 w = *(const float4*)&W0s[c * 64 + 4 * dgrp];
          acc[0][0] = fmaf(a.x, w.x, acc[0][0]); acc[0][1] = fmaf(a.x, w.y, acc[0][1]);
          acc[0][2] = fmaf(a.x, w.z, acc[0][2]); acc[0][3] = fmaf(a.x, w.w, acc[0][3]);
          acc[1][0] = fmaf(a.y, w.x, acc[1][0]); acc[1][1] = fmaf(a.y, w.y, acc[1][1]);
          acc[1][2] = fmaf(a.y, w.z, acc[1][2]); acc[1][3] = fmaf(a.y, w.w, acc[1][3]);
        }
#pragma unroll
        for (int dj = 0; dj < 4; ++dj) {
          const int d = 4 * dgrp + dj;
          const float s = s0c[d], bb = t0c[d];
#pragma unroll
          for (int si = 0; si < 2; ++si) {
            float yv = fmaf(acc[si][dj], s, bb);
            h0T[d * 34 + 2 * sgrp + si] = fmaxf(yv, 0.0f);
          }
        }
      }
      __syncthreads();
      // ---- L1: 64 -> 64 ----
      {
        float acc[2][4] = {{0, 0, 0, 0}, {0, 0, 0, 0}};
#pragma unroll 4
        for (int c = 0; c < 64; ++c) {
          const float2 a = *(const float2*)&h0T[c * 34 + 2 * sgrp];
          const float4 w = *(const float4*)&W1s[c * 64 + 4 * dgrp];
          acc[0][0] = fmaf(a.x, w.x, acc[0][0]); acc[0][1] = fmaf(a.x, w.y, acc[0][1]);
          acc[0][2] = fmaf(a.x, w.z, acc[0][2]); acc[0][3] = fmaf(a.x, w.w, acc[0][3]);
          acc[1][0] = fmaf(a.y, w.x, acc[1][0]); acc[1][1] = fmaf(a.y, w.y, acc[1][1]);
          acc[1][2] = fmaf(a.y, w.z, acc[1][2]); acc[1][3] = fmaf(a.y, w.w, acc[1][3]);
        }
#pragma unroll
        for (int dj = 0; dj < 4; ++dj) {
          const int d = 4 * dgrp + dj;
          const float s = s1c[d], bb = t1c[d];
#pragma unroll
          for (int si = 0; si < 2; ++si) {
            float yv = fmaf(acc[si][dj], s, bb);
            h1T[d * 36 + 2 * sgrp + si] = fmaxf(yv, 0.0f);
          }
        }
      }
      __syncthreads();
      // ---- L2: 64 -> 128, fused BN+ReLU+max ----
      {
        float acc[4][4] = {{0,0,0,0},{0,0,0,0},{0,0,0,0},{0,0,0,0}};
#pragma unroll 8
        for (int c = 0; c < 64; ++c) {
          const float4 a = *(const float4*)&h1T[c * 36 + 4 * sg2];
          const float4 w = *(const float4*)(W2 + c * 128 + 4 * dg2);
          acc[0][0] = fmaf(a.x, w.x, acc[0][0]); acc[0][1] = fmaf(a.x, w.y, acc[0][1]);
          acc[0][2] = fmaf(a.x, w.z, acc[0][2]); acc[0][3] = fmaf(a.x, w.w, acc[0][3]);
          acc[1][0] = fmaf(a.y, w.x, acc[1][0]); acc[1][1] = fmaf(a.y, w.y, acc[1][1]);
          acc[1][2] = fmaf(a.y, w.z, acc[1][2]); acc[1][3] = fmaf(a.y, w.w, acc[1][3]);
          acc[2][0] = fmaf(a.z, w.x, acc[2][0]); acc[2][1] = fmaf(a.z, w.y, acc[2][1]);
          acc[2][2] = fmaf(a.z, w.z, acc[2][2]); acc[2][3] = fmaf(a.z, w.w, acc[2][3]);
          acc[3][0] = fmaf(a.w, w.x, acc[3][0]); acc[3][1] = fmaf(a.w, w.y, acc[3][1]);
          acc[3][2] = fmaf(a.w, w.z, acc[3][2]); acc[3][3] = fmaf(a.w, w.w, acc[3][3]);
        }
#pragma unroll
        for (int dj = 0; dj < 4; ++dj) {
          const int d = 4 * dg2 + dj;
          const float s = s2c[d], bb = t2c[d];
          float mx = 0.0f;  // relu outputs are >= 0
#pragma unroll
          for (int si = 0; si < 4; ++si) {
            float yv = fmaf(acc[si][dj], s, bb);
            mx = fmaxf(mx, fmaxf(yv, 0.0f));
          }
          pmax[sg2 * 128 + d] = mx;
        }
      }
      __syncthreads();
      if (t < 128) {
        float mx = pmax[t];
#pragma unroll
        for (int g = 1; g < 8; ++g) mx = fmaxf(mx, pmax[g * 128 + t]);
        new_points[(size_t)pg * 128 + t] = mx;
      }
      __syncthreads();
    }
  };

  if (bid >= 256) {
    // 256 tail blocks, TWO sequential single-centroid pipelines each:
    // first (b, 960+q) — ready at the early-992 publish, overlaps chunk 31;
    // then (b, 992+q) — ready at the final publish (true end-phase ~10us).
    const int sid = bid - 256;          // 0..255
    const int b = sid & 7;              // spread across batches/XCDs
    const int q = sid >> 3;             // 0..31
    wait_prog(b, (unsigned)(960 + q + 1));
    process_group(b, 960 + q, 1);
    wait_prog(b, (unsigned)(992 + q + 1));
    process_group(b, 992 + q, 1);
  } else {
    // 248 normal workers: j=0..239 (centroids 0..959), ready-order k = j*8+b.
    for (int k = bid - 8; k < 1920; k += 248) {
      const int j = k >> 3, b = k & 7;
      wait_prog(b, (unsigned)(j * 4 + 4));
      process_group(b, j * 4, 4);
    }
  }
}

extern "C" void kernel_launch(void* const* d_in, const int* in_sizes, int n_in,
                              void* d_out, int out_size, void* d_ws, size_t ws_size,
                              hipStream_t stream) {
  (void)in_sizes; (void)n_in; (void)out_size; (void)ws_size;
  const float* xyz    = (const float*)d_in[0];
  const float* points = (const float*)d_in[1];
  const float* W0 = (const float*)d_in[2];
  const float* g0 = (const float*)d_in[3];
  const float* b0 = (const float*)d_in[4];
  const float* m0 = (const float*)d_in[5];
  const float* v0 = (const float*)d_in[6];
  const float* W1 = (const float*)d_in[7];
  const float* g1 = (const float*)d_in[8];
  const float* b1 = (const float*)d_in[9];
  const float* m1 = (const float*)d_in[10];
  const float* v1 = (const float*)d_in[11];
  const float* W2 = (const float*)d_in[12];
  const float* g2 = (const float*)d_in[13];
  const float* b2 = (const float*)d_in[14];
  const float* m2 = (const float*)d_in[15];
  const float* v2 = (const float*)d_in[16];

  float* new_xyz    = (float*)d_out;                 // 8*1024*3
  float* new_points = new_xyz + 8 * 1024 * 3;        // 8*1024*128
  float* idxf       = new_points + 8 * 1024 * 128;   // 8*1024*32

  unsigned int* prog = (unsigned int*)d_ws;          // 8 counters, 128B apart
  (void)hipMemsetAsync(d_ws, 0, 8 * 32 * sizeof(unsigned int), stream);
  fused_kernel<<<512, 256, 0, stream>>>(xyz, points, W0, g0, b0, m0, v0,
                                        W1, g1, b1, m1, v1,
                                        W2, g2, b2, m2, v2,
                                        new_xyz, new_points, idxf, prog);
}